// Round 2
// baseline (231.919 us; speedup 1.0000x reference)
//
#include <hip/hip_runtime.h>
#include <stdint.h>

// Problem constants (B, N, D, QM, QP, NP, T) = (16, 900, 256, 4, 4, 6, 4)
// Storage model (established R0-R3): float arrays are bf16-ROUNDED values in
// FLOAT32 containers; output buffer is FLOAT32 (out_size floats). Bool/int
// input storage is detected at runtime (i32 / u8 / bf16 / f32).
//
// R4/R5: persistent grid-stride kernel, 1024 blocks.
//  - detection runs 1024x instead of 12,683x (was once per 256-thread block)
//  - unroll-by-4 over grid-stride: 4 independent 32B loads in flight per lane
//    (memory-level parallelism was the limiter: 2.3 TB/s of 6.3 achievable)
//  - nontemporal stores via native ext_vector type (HIP float4 is a struct
//    and is rejected by __builtin_nontemporal_store — R4 compile failure)
namespace {
constexpr int Bn = 16, Nn = 900, Dn = 256, QMn = 4, QPn = 4, NPn = 6, Tn = 4;

constexpr int SZ_MQ  = Bn * QMn * Nn * Dn;        // 14,745,600
constexpr int SZ_PQ  = Bn * QPn * NPn * Dn;       //     98,304
constexpr int SZ_EQ  = Bn * QPn * Dn;             //     16,384
constexpr int SZ_PER = Bn * QMn;                  //         64
constexpr int SZ_MM  = Bn * (Tn - 1) * Nn;        //     43,200
constexpr int SZ_ME  = Bn * (Tn - 1) * Nn * Dn;   // 11,059,200
constexpr int SZ_PM  = Bn * (Tn - 1);             //         48
constexpr int SZ_PE  = Bn * (Tn - 1) * Dn;        //     12,288

constexpr int OFF_MQ  = 0;
constexpr int OFF_PQ  = OFF_MQ + SZ_MQ;
constexpr int OFF_EQ  = OFF_PQ + SZ_PQ;
constexpr int OFF_PER = OFF_EQ + SZ_EQ;
constexpr int OFF_MM  = OFF_PER + SZ_PER;
constexpr int OFF_ME  = OFF_MM + SZ_MM;
constexpr int OFF_PM  = OFF_ME + SZ_ME;
constexpr int OFF_PE  = OFF_PM + SZ_PM;
constexpr int TOTAL   = OFF_PE + SZ_PE;           // 25,975,088 (divisible by 8)
constexpr int NPACKS  = TOTAL / 8;                // 3,246,886
}  // namespace

using u16 = unsigned short;
typedef float f32x4 __attribute__((ext_vector_type(4)));   // native vec for NT store

__device__ __forceinline__ float bits_to_f(unsigned u) {
    return __builtin_bit_cast(float, u);
}

// ---------------- runtime storage-mode detection ----------------
// Float arrays: 0 = f32 container, 1 = bf16 container.
__device__ int detect_float_mode(const void* p) {
    const unsigned* w = (const unsigned*)p;
    int cnt = 0;
#pragma unroll
    for (int i = 0; i < 32; ++i) {
        unsigned ex = (w[i] >> 7) & 0xFFu;   // bf16 exponent field of low halfword
        cnt += (ex >= 120u && ex <= 133u) ? 1 : 0;
    }
    return (cnt >= 16) ? 1 : 0;
}

enum { BM_I32 = 0, BM_U8 = 1, BM_BF16 = 2, BM_F32 = 3 };
__device__ int detect_bool_mode(const void* p) {
    const unsigned* w = (const unsigned*)p;
    unsigned orw = 0, or_even = 0;
    bool hw_ok = true, u8_ok = true;
#pragma unroll
    for (int i = 0; i < 64; ++i) {
        unsigned x = w[i];
        orw |= x;
        unsigned lo = x & 0xFFFFu, hi = x >> 16;
        hw_ok = hw_ok && (lo == 0u || lo == 0x3F80u) && (hi == 0u || hi == 0x3F80u);
        or_even |= lo;
        u8_ok = u8_ok && ((x & 0xFEFEFEFEu) == 0u);
    }
    if (orw <= 1u) return BM_I32;
    if (hw_ok)     return (or_even == 0u) ? BM_F32 : BM_BF16;
    if (u8_ok)     return BM_U8;
    return BM_I32;
}

__device__ __forceinline__ bool get_bool(const void* p, int i, int m) {
    if (m == BM_I32) return ((const int*)p)[i] != 0;
    if (m == BM_U8)  return ((const unsigned char*)p)[i] != 0;
    if (m == BM_BF16) return ((const u16*)p)[i] != 0;
    return ((const unsigned*)p)[i] != 0;     // F32: 0x3F800000 / 0
}

// period (values {0,1,2,3}): 0 = i32, 1 = bf16, 2 = f32.
__device__ int detect_period_mode(const void* p) {
    const unsigned* w = (const unsigned*)p;
    unsigned orw = 0, or_even = 0;
    bool hw_ok = true;
#pragma unroll
    for (int i = 0; i < 16; ++i) {
        unsigned x = w[i];
        orw |= x;
        unsigned lo = x & 0xFFFFu, hi = x >> 16;
        bool lo_ok = (lo == 0u || lo == 0x3F80u || lo == 0x4000u || lo == 0x4040u);
        bool hi_ok = (hi == 0u || hi == 0x3F80u || hi == 0x4000u || hi == 0x4040u);
        hw_ok = hw_ok && lo_ok && hi_ok;
        or_even |= lo;
    }
    if (orw <= 3u) return 0;
    if (hw_ok && or_even == 0u) return 2;
    return 1;
}

__device__ __forceinline__ float get_period_f(const void* p, int i, int m) {
    if (m == 0) return (float)((const int*)p)[i];
    if (m == 1) return bits_to_f((unsigned)((const u16*)p)[i] << 16);
    return ((const float*)p)[i];
}

// Load 8 contiguous float-typed elements starting at element e -> two float4.
__device__ __forceinline__ void load8f(const void* base, int e, int fm,
                                       float4& A, float4& B) {
    if (fm == 0) {
        const float* f = (const float*)base + e;
        A = reinterpret_cast<const float4*>(f)[0];
        B = reinterpret_cast<const float4*>(f)[1];
    } else {
        const int4 r = *reinterpret_cast<const int4*>((const u16*)base + e);
        unsigned x;
        x = (unsigned)r.x; A.x = bits_to_f(x << 16); A.y = bits_to_f(x & 0xFFFF0000u);
        x = (unsigned)r.y; A.z = bits_to_f(x << 16); A.w = bits_to_f(x & 0xFFFF0000u);
        x = (unsigned)r.z; B.x = bits_to_f(x << 16); B.y = bits_to_f(x & 0xFFFF0000u);
        x = (unsigned)r.w; B.z = bits_to_f(x << 16); B.w = bits_to_f(x & 0xFFFF0000u);
    }
}

// Compute one 8-float pack (pack index in [0, NPACKS)) into A, B.
__device__ __forceinline__ void compute_pack(
    int pack, int fm, int bm, int pmode,
    const void* __restrict__ motion_query,
    const void* __restrict__ plan_query,
    const void* __restrict__ ego_status_feature,
    const void* __restrict__ motion_queue,
    const void* __restrict__ plan_queue,
    const void* __restrict__ ego_status_queue,
    const void* __restrict__ period,
    const void* __restrict__ mask,
    const void* __restrict__ temp_anchor,
    const void* __restrict__ temp_mask,
    const void* __restrict__ ego_anchor,
    const void* __restrict__ ego_mask,
    float4& A, float4& B)
{
    const int idx = pack * 8;

    if (idx < OFF_PQ) {
        // ---- mq: out[b,q,n,d] = reset ? motion_query[b,n,d] : motion_queue[b,q,n,d]
        const int e = idx - OFF_MQ;
        const int d = e & (Dn - 1);
        const unsigned row = (unsigned)(e >> 8);     // (b*QM+q)*N + n
        const unsigned bq = row / (unsigned)Nn;
        const unsigned n = row - bq * (unsigned)Nn;
        const unsigned b = bq >> 2;
        const bool reset = !get_bool(mask, (int)b, bm);
        if (reset) load8f(motion_query, (((int)b * Nn + (int)n) << 8) + d, fm, A, B);
        else       load8f(motion_queue, e, fm, A, B);
    } else if (idx < OFF_EQ) {
        // ---- pq
        const int e = idx - OFF_PQ;
        const int d = e & (Dn - 1);
        const unsigned row = (unsigned)(e >> 8);     // (b*QP+q)*NP + p
        const unsigned b = row / (unsigned)(QPn * NPn);
        const unsigned rem = row - b * (unsigned)(QPn * NPn);
        const unsigned q = rem / (unsigned)NPn;
        const unsigned p = rem - q * (unsigned)NPn;
        const bool reset = !get_bool(mask, (int)b, bm);
        if (reset) load8f(plan_query, (((int)b * NPn + (int)p) << 8) + d, fm, A, B);
        else       load8f(plan_queue, e, fm, A, B);
    } else if (idx < OFF_PER) {
        // ---- eq
        const int e = idx - OFF_EQ;
        const int d = e & (Dn - 1);
        const int row = e >> 8;                      // b*QP + q
        const int b = row >> 2;
        const bool reset = !get_bool(mask, b, bm);
        if (reset) load8f(ego_status_feature, (b << 8) + d, fm, A, B);
        else       load8f(ego_status_queue, e, fm, A, B);
    } else if (idx < OFF_MM) {
        // ---- per: out[b,q] = reset ? 0 : period[b,q]
        const int e = idx - OFF_PER;
        float h[8];
#pragma unroll
        for (int k = 0; k < 8; ++k) {
            const int g = e + k;
            const int b = g >> 2;
            const bool reset = !get_bool(mask, b, bm);
            h[k] = reset ? 0.0f : get_period_f(period, g, pmode);
        }
        A = make_float4(h[0], h[1], h[2], h[3]);
        B = make_float4(h[4], h[5], h[6], h[7]);
    } else if (idx < OFF_ME) {
        // ---- mm (transposed): out[b,t,n] = temp_mask[b,n,t], t < T-1
        const int e = idx - OFF_MM;
        float h[8];
#pragma unroll
        for (int k = 0; k < 8; ++k) {
            const unsigned g = (unsigned)(e + k);
            const unsigned b = g / (unsigned)((Tn - 1) * Nn);
            const unsigned rem = g - b * (unsigned)((Tn - 1) * Nn);
            const unsigned t = rem / (unsigned)Nn;
            const unsigned n = rem - t * (unsigned)Nn;
            h[k] = get_bool(temp_mask, ((int)b * Nn + (int)n) * Tn + (int)t, bm)
                       ? 1.0f : 0.0f;
        }
        A = make_float4(h[0], h[1], h[2], h[3]);
        B = make_float4(h[4], h[5], h[6], h[7]);
    } else if (idx < OFF_PM) {
        // ---- me (transposed): out[b,t,n,d] = temp_anchor[b,n,t,d], t < T-1
        const int e = idx - OFF_ME;
        const int d = e & (Dn - 1);
        const unsigned row = (unsigned)(e >> 8);     // b*(T-1)*N + t*N + n
        const unsigned b = row / (unsigned)((Tn - 1) * Nn);
        const unsigned rem = row - b * (unsigned)((Tn - 1) * Nn);
        const unsigned t = rem / (unsigned)Nn;
        const unsigned n = rem - t * (unsigned)Nn;
        load8f(temp_anchor, ((((int)b * Nn + (int)n) * Tn + (int)t) << 8) + d, fm, A, B);
    } else if (idx < OFF_PE) {
        // ---- pm (transposed, unmodified): out[b,t,0] = ego_mask[b,0,t]
        const int e = idx - OFF_PM;
        float h[8];
#pragma unroll
        for (int k = 0; k < 8; ++k) {
            const unsigned g = (unsigned)(e + k);
            const unsigned b = g / (unsigned)(Tn - 1);
            const unsigned t = g - b * (unsigned)(Tn - 1);
            h[k] = get_bool(ego_mask, (int)b * Tn + (int)t, bm) ? 1.0f : 0.0f;
        }
        A = make_float4(h[0], h[1], h[2], h[3]);
        B = make_float4(h[4], h[5], h[6], h[7]);
    } else {
        // ---- pe (transposed + overwrite): out[b,t,0,d]
        const int e = idx - OFF_PE;
        const int d = e & (Dn - 1);
        const unsigned row = (unsigned)(e >> 8);     // b*(T-1) + t
        const unsigned b = row / (unsigned)(Tn - 1);
        const unsigned t = row - b * (unsigned)(Tn - 1);

        bool any_flag = false;
#pragma unroll
        for (int bb = 0; bb < Bn; ++bb) {
            any_flag = any_flag || get_bool(ego_mask, bb * Tn + 0, bm)
                                || get_bool(ego_mask, bb * Tn + 1, bm)
                                || get_bool(ego_mask, bb * Tn + 2, bm);
        }

        const bool p0 = get_bool(ego_mask, (int)b * Tn + 0, bm);
        const bool p1 = get_bool(ego_mask, (int)b * Tn + 1, bm);
        const bool p2 = get_bool(ego_mask, (int)b * Tn + 2, bm);
        const bool all_true = p0 && p1 && p2;
        const int first_false = (!p0) ? 0 : ((!p1) ? 1 : ((!p2) ? 2 : 0));

        const bool overwrite = all_true || ((int)t < first_false);
        int src_t = (int)t;
        if (any_flag && overwrite) src_t = all_true ? (Tn - 1) : first_false;

        load8f(ego_anchor, (((int)b * Tn + src_t) << 8) + d, fm, A, B);
    }
}

__device__ __forceinline__ void store_pack_nt(float* __restrict__ out, int pack,
                                              const float4& A, const float4& B) {
    f32x4* p = reinterpret_cast<f32x4*>(out + pack * 8);
    __builtin_nontemporal_store(__builtin_bit_cast(f32x4, A), p);
    __builtin_nontemporal_store(__builtin_bit_cast(f32x4, B), p + 1);
}

__global__ __launch_bounds__(256) void state_queue_kernel(
    const void* __restrict__ motion_query,        // (B,N,D) float-typed
    const void* __restrict__ plan_query,          // (B,NP,D)
    const void* __restrict__ ego_status_feature,  // (B,D)
    const void* __restrict__ motion_queue,        // (B,QM,N,D)
    const void* __restrict__ plan_queue,          // (B,QP,NP,D)
    const void* __restrict__ ego_status_queue,    // (B,QP,D)
    const void* __restrict__ period,              // (B,QM) int-typed
    const void* __restrict__ mask,                // (B,) bool-typed
    const void* __restrict__ temp_anchor,         // (B,N,T,D)
    const void* __restrict__ temp_mask,           // (B,N,T) bool-typed
    const void* __restrict__ ego_anchor,          // (B,1,T,D)
    const void* __restrict__ ego_mask,            // (B,1,T) bool-typed
    float* __restrict__ out)
{
    __shared__ int s_modes[3];
    if (threadIdx.x == 0) {
        s_modes[0] = detect_float_mode(motion_query);
        s_modes[1] = detect_bool_mode(temp_mask);
        s_modes[2] = detect_period_mode(period);
    }
    __syncthreads();
    const int fm = s_modes[0];
    const int bm = s_modes[1];
    const int pmode = s_modes[2];

    const int stride = (int)(gridDim.x * blockDim.x);
    int pack = (int)(blockIdx.x * blockDim.x + threadIdx.x);

    // Main loop: 4 independent packs in flight per thread (4x MLP).
    for (; pack + 3 * stride < NPACKS; pack += 4 * stride) {
        float4 A0, B0, A1, B1, A2, B2, A3, B3;
        compute_pack(pack + 0 * stride, fm, bm, pmode,
                     motion_query, plan_query, ego_status_feature, motion_queue,
                     plan_queue, ego_status_queue, period, mask, temp_anchor,
                     temp_mask, ego_anchor, ego_mask, A0, B0);
        compute_pack(pack + 1 * stride, fm, bm, pmode,
                     motion_query, plan_query, ego_status_feature, motion_queue,
                     plan_queue, ego_status_queue, period, mask, temp_anchor,
                     temp_mask, ego_anchor, ego_mask, A1, B1);
        compute_pack(pack + 2 * stride, fm, bm, pmode,
                     motion_query, plan_query, ego_status_feature, motion_queue,
                     plan_queue, ego_status_queue, period, mask, temp_anchor,
                     temp_mask, ego_anchor, ego_mask, A2, B2);
        compute_pack(pack + 3 * stride, fm, bm, pmode,
                     motion_query, plan_query, ego_status_feature, motion_queue,
                     plan_queue, ego_status_queue, period, mask, temp_anchor,
                     temp_mask, ego_anchor, ego_mask, A3, B3);
        store_pack_nt(out, pack + 0 * stride, A0, B0);
        store_pack_nt(out, pack + 1 * stride, A1, B1);
        store_pack_nt(out, pack + 2 * stride, A2, B2);
        store_pack_nt(out, pack + 3 * stride, A3, B3);
    }
    // Tail.
    for (; pack < NPACKS; pack += stride) {
        float4 A, B;
        compute_pack(pack, fm, bm, pmode,
                     motion_query, plan_query, ego_status_feature, motion_queue,
                     plan_queue, ego_status_queue, period, mask, temp_anchor,
                     temp_mask, ego_anchor, ego_mask, A, B);
        store_pack_nt(out, pack, A, B);
    }
}

extern "C" void kernel_launch(void* const* d_in, const int* in_sizes, int n_in,
                              void* d_out, int out_size, void* d_ws, size_t ws_size,
                              hipStream_t stream) {
    float* out = (float*)d_out;
    const int threads = 256;
    const int blocks = 1024;   // persistent-ish: ~12.4 packs/thread, 4 blocks/CU
    state_queue_kernel<<<blocks, threads, 0, stream>>>(
        d_in[0], d_in[1], d_in[2], d_in[3], d_in[4], d_in[5], d_in[6], d_in[7],
        d_in[8], d_in[9], d_in[10], d_in[11], out);
}

// Round 5
// 226.002 us; speedup vs baseline: 1.0262x; 1.0262x over previous
//
#include <hip/hip_runtime.h>
#include <stdint.h>

// Problem constants (B, N, D, QM, QP, NP, T) = (16, 900, 256, 4, 4, 6, 4)
// Storage model (established R0-R3): float arrays are bf16-ROUNDED values in
// FLOAT32 containers; output buffer is FLOAT32 (out_size floats). Bool/int
// input storage is detected at runtime (i32 / u8 / bf16 / f32).
//
// R6/R7/R8: persistent grid-stride, full occupancy, normal stores.
//  - R5 post-mortem: NT stores amplified HBM writes +14% (no L2 write-combine);
//    1024 blocks capped occupancy at 37%; dur tracked 1/occupancy.
//  - This round: 4096 blocks (8 resident/CU = 32 waves/CU), plain float4
//    stores, NO manual unroll (VGPR low; TLP hides latency per R5 scaling).
//  - Detection runs 4096x (vs 12,683x in baseline); dispatch-rate pressure
//    removed (baseline needed ~186 WG/us from the CP).
//  (R8 = R6 resubmitted: R3 hit GPUAcquisitionTimeout, R4 hit container
//   failure — kernel has never run.)
namespace {
constexpr int Bn = 16, Nn = 900, Dn = 256, QMn = 4, QPn = 4, NPn = 6, Tn = 4;

constexpr int SZ_MQ  = Bn * QMn * Nn * Dn;        // 14,745,600
constexpr int SZ_PQ  = Bn * QPn * NPn * Dn;       //     98,304
constexpr int SZ_EQ  = Bn * QPn * Dn;             //     16,384
constexpr int SZ_PER = Bn * QMn;                  //         64
constexpr int SZ_MM  = Bn * (Tn - 1) * Nn;        //     43,200
constexpr int SZ_ME  = Bn * (Tn - 1) * Nn * Dn;   // 11,059,200
constexpr int SZ_PM  = Bn * (Tn - 1);             //         48
constexpr int SZ_PE  = Bn * (Tn - 1) * Dn;        //     12,288

constexpr int OFF_MQ  = 0;
constexpr int OFF_PQ  = OFF_MQ + SZ_MQ;
constexpr int OFF_EQ  = OFF_PQ + SZ_PQ;
constexpr int OFF_PER = OFF_EQ + SZ_EQ;
constexpr int OFF_MM  = OFF_PER + SZ_PER;
constexpr int OFF_ME  = OFF_MM + SZ_MM;
constexpr int OFF_PM  = OFF_ME + SZ_ME;
constexpr int OFF_PE  = OFF_PM + SZ_PM;
constexpr int TOTAL   = OFF_PE + SZ_PE;           // 25,975,088 (divisible by 8)
constexpr int NPACKS  = TOTAL / 8;                // 3,246,886
}  // namespace

using u16 = unsigned short;

__device__ __forceinline__ float bits_to_f(unsigned u) {
    return __builtin_bit_cast(float, u);
}

// ---------------- runtime storage-mode detection ----------------
// Float arrays: 0 = f32 container, 1 = bf16 container.
__device__ int detect_float_mode(const void* p) {
    const unsigned* w = (const unsigned*)p;
    int cnt = 0;
#pragma unroll
    for (int i = 0; i < 32; ++i) {
        unsigned ex = (w[i] >> 7) & 0xFFu;   // bf16 exponent field of low halfword
        cnt += (ex >= 120u && ex <= 133u) ? 1 : 0;
    }
    return (cnt >= 16) ? 1 : 0;
}

enum { BM_I32 = 0, BM_U8 = 1, BM_BF16 = 2, BM_F32 = 3 };
__device__ int detect_bool_mode(const void* p) {
    const unsigned* w = (const unsigned*)p;
    unsigned orw = 0, or_even = 0;
    bool hw_ok = true, u8_ok = true;
#pragma unroll
    for (int i = 0; i < 64; ++i) {
        unsigned x = w[i];
        orw |= x;
        unsigned lo = x & 0xFFFFu, hi = x >> 16;
        hw_ok = hw_ok && (lo == 0u || lo == 0x3F80u) && (hi == 0u || hi == 0x3F80u);
        or_even |= lo;
        u8_ok = u8_ok && ((x & 0xFEFEFEFEu) == 0u);
    }
    if (orw <= 1u) return BM_I32;
    if (hw_ok)     return (or_even == 0u) ? BM_F32 : BM_BF16;
    if (u8_ok)     return BM_U8;
    return BM_I32;
}

__device__ __forceinline__ bool get_bool(const void* p, int i, int m) {
    if (m == BM_I32) return ((const int*)p)[i] != 0;
    if (m == BM_U8)  return ((const unsigned char*)p)[i] != 0;
    if (m == BM_BF16) return ((const u16*)p)[i] != 0;
    return ((const unsigned*)p)[i] != 0;     // F32: 0x3F800000 / 0
}

// period (values {0,1,2,3}): 0 = i32, 1 = bf16, 2 = f32.
__device__ int detect_period_mode(const void* p) {
    const unsigned* w = (const unsigned*)p;
    unsigned orw = 0, or_even = 0;
    bool hw_ok = true;
#pragma unroll
    for (int i = 0; i < 16; ++i) {
        unsigned x = w[i];
        orw |= x;
        unsigned lo = x & 0xFFFFu, hi = x >> 16;
        bool lo_ok = (lo == 0u || lo == 0x3F80u || lo == 0x4000u || lo == 0x4040u);
        bool hi_ok = (hi == 0u || hi == 0x3F80u || hi == 0x4000u || hi == 0x4040u);
        hw_ok = hw_ok && lo_ok && hi_ok;
        or_even |= lo;
    }
    if (orw <= 3u) return 0;
    if (hw_ok && or_even == 0u) return 2;
    return 1;
}

__device__ __forceinline__ float get_period_f(const void* p, int i, int m) {
    if (m == 0) return (float)((const int*)p)[i];
    if (m == 1) return bits_to_f((unsigned)((const u16*)p)[i] << 16);
    return ((const float*)p)[i];
}

// Load 8 contiguous float-typed elements starting at element e -> two float4.
__device__ __forceinline__ void load8f(const void* base, int e, int fm,
                                       float4& A, float4& B) {
    if (fm == 0) {
        const float* f = (const float*)base + e;
        A = reinterpret_cast<const float4*>(f)[0];
        B = reinterpret_cast<const float4*>(f)[1];
    } else {
        const int4 r = *reinterpret_cast<const int4*>((const u16*)base + e);
        unsigned x;
        x = (unsigned)r.x; A.x = bits_to_f(x << 16); A.y = bits_to_f(x & 0xFFFF0000u);
        x = (unsigned)r.y; A.z = bits_to_f(x << 16); A.w = bits_to_f(x & 0xFFFF0000u);
        x = (unsigned)r.z; B.x = bits_to_f(x << 16); B.y = bits_to_f(x & 0xFFFF0000u);
        x = (unsigned)r.w; B.z = bits_to_f(x << 16); B.w = bits_to_f(x & 0xFFFF0000u);
    }
}

// Compute one 8-float pack (pack index in [0, NPACKS)) into A, B.
__device__ __forceinline__ void compute_pack(
    int pack, int fm, int bm, int pmode,
    const void* __restrict__ motion_query,
    const void* __restrict__ plan_query,
    const void* __restrict__ ego_status_feature,
    const void* __restrict__ motion_queue,
    const void* __restrict__ plan_queue,
    const void* __restrict__ ego_status_queue,
    const void* __restrict__ period,
    const void* __restrict__ mask,
    const void* __restrict__ temp_anchor,
    const void* __restrict__ temp_mask,
    const void* __restrict__ ego_anchor,
    const void* __restrict__ ego_mask,
    float4& A, float4& B)
{
    const int idx = pack * 8;

    if (idx < OFF_PQ) {
        // ---- mq: out[b,q,n,d] = reset ? motion_query[b,n,d] : motion_queue[b,q,n,d]
        const int e = idx - OFF_MQ;
        const int d = e & (Dn - 1);
        const unsigned row = (unsigned)(e >> 8);     // (b*QM+q)*N + n
        const unsigned bq = row / (unsigned)Nn;
        const unsigned n = row - bq * (unsigned)Nn;
        const unsigned b = bq >> 2;
        const bool reset = !get_bool(mask, (int)b, bm);
        if (reset) load8f(motion_query, (((int)b * Nn + (int)n) << 8) + d, fm, A, B);
        else       load8f(motion_queue, e, fm, A, B);
    } else if (idx < OFF_EQ) {
        // ---- pq
        const int e = idx - OFF_PQ;
        const int d = e & (Dn - 1);
        const unsigned row = (unsigned)(e >> 8);     // (b*QP+q)*NP + p
        const unsigned b = row / (unsigned)(QPn * NPn);
        const unsigned rem = row - b * (unsigned)(QPn * NPn);
        const unsigned q = rem / (unsigned)NPn;
        const unsigned p = rem - q * (unsigned)NPn;
        const bool reset = !get_bool(mask, (int)b, bm);
        if (reset) load8f(plan_query, (((int)b * NPn + (int)p) << 8) + d, fm, A, B);
        else       load8f(plan_queue, e, fm, A, B);
    } else if (idx < OFF_PER) {
        // ---- eq
        const int e = idx - OFF_EQ;
        const int d = e & (Dn - 1);
        const int row = e >> 8;                      // b*QP + q
        const int b = row >> 2;
        const bool reset = !get_bool(mask, b, bm);
        if (reset) load8f(ego_status_feature, (b << 8) + d, fm, A, B);
        else       load8f(ego_status_queue, e, fm, A, B);
    } else if (idx < OFF_MM) {
        // ---- per: out[b,q] = reset ? 0 : period[b,q]
        const int e = idx - OFF_PER;
        float h[8];
#pragma unroll
        for (int k = 0; k < 8; ++k) {
            const int g = e + k;
            const int b = g >> 2;
            const bool reset = !get_bool(mask, b, bm);
            h[k] = reset ? 0.0f : get_period_f(period, g, pmode);
        }
        A = make_float4(h[0], h[1], h[2], h[3]);
        B = make_float4(h[4], h[5], h[6], h[7]);
    } else if (idx < OFF_ME) {
        // ---- mm (transposed): out[b,t,n] = temp_mask[b,n,t], t < T-1
        const int e = idx - OFF_MM;
        float h[8];
#pragma unroll
        for (int k = 0; k < 8; ++k) {
            const unsigned g = (unsigned)(e + k);
            const unsigned b = g / (unsigned)((Tn - 1) * Nn);
            const unsigned rem = g - b * (unsigned)((Tn - 1) * Nn);
            const unsigned t = rem / (unsigned)Nn;
            const unsigned n = rem - t * (unsigned)Nn;
            h[k] = get_bool(temp_mask, ((int)b * Nn + (int)n) * Tn + (int)t, bm)
                       ? 1.0f : 0.0f;
        }
        A = make_float4(h[0], h[1], h[2], h[3]);
        B = make_float4(h[4], h[5], h[6], h[7]);
    } else if (idx < OFF_PM) {
        // ---- me (transposed): out[b,t,n,d] = temp_anchor[b,n,t,d], t < T-1
        const int e = idx - OFF_ME;
        const int d = e & (Dn - 1);
        const unsigned row = (unsigned)(e >> 8);     // b*(T-1)*N + t*N + n
        const unsigned b = row / (unsigned)((Tn - 1) * Nn);
        const unsigned rem = row - b * (unsigned)((Tn - 1) * Nn);
        const unsigned t = rem / (unsigned)Nn;
        const unsigned n = rem - t * (unsigned)Nn;
        load8f(temp_anchor, ((((int)b * Nn + (int)n) * Tn + (int)t) << 8) + d, fm, A, B);
    } else if (idx < OFF_PE) {
        // ---- pm (transposed, unmodified): out[b,t,0] = ego_mask[b,0,t]
        const int e = idx - OFF_PM;
        float h[8];
#pragma unroll
        for (int k = 0; k < 8; ++k) {
            const unsigned g = (unsigned)(e + k);
            const unsigned b = g / (unsigned)(Tn - 1);
            const unsigned t = g - b * (unsigned)(Tn - 1);
            h[k] = get_bool(ego_mask, (int)b * Tn + (int)t, bm) ? 1.0f : 0.0f;
        }
        A = make_float4(h[0], h[1], h[2], h[3]);
        B = make_float4(h[4], h[5], h[6], h[7]);
    } else {
        // ---- pe (transposed + overwrite): out[b,t,0,d]
        const int e = idx - OFF_PE;
        const int d = e & (Dn - 1);
        const unsigned row = (unsigned)(e >> 8);     // b*(T-1) + t
        const unsigned b = row / (unsigned)(Tn - 1);
        const unsigned t = row - b * (unsigned)(Tn - 1);

        bool any_flag = false;
#pragma unroll
        for (int bb = 0; bb < Bn; ++bb) {
            any_flag = any_flag || get_bool(ego_mask, bb * Tn + 0, bm)
                                || get_bool(ego_mask, bb * Tn + 1, bm)
                                || get_bool(ego_mask, bb * Tn + 2, bm);
        }

        const bool p0 = get_bool(ego_mask, (int)b * Tn + 0, bm);
        const bool p1 = get_bool(ego_mask, (int)b * Tn + 1, bm);
        const bool p2 = get_bool(ego_mask, (int)b * Tn + 2, bm);
        const bool all_true = p0 && p1 && p2;
        const int first_false = (!p0) ? 0 : ((!p1) ? 1 : ((!p2) ? 2 : 0));

        const bool overwrite = all_true || ((int)t < first_false);
        int src_t = (int)t;
        if (any_flag && overwrite) src_t = all_true ? (Tn - 1) : first_false;

        load8f(ego_anchor, (((int)b * Tn + src_t) << 8) + d, fm, A, B);
    }
}

__global__ __launch_bounds__(256) void state_queue_kernel(
    const void* __restrict__ motion_query,        // (B,N,D) float-typed
    const void* __restrict__ plan_query,          // (B,NP,D)
    const void* __restrict__ ego_status_feature,  // (B,D)
    const void* __restrict__ motion_queue,        // (B,QM,N,D)
    const void* __restrict__ plan_queue,          // (B,QP,NP,D)
    const void* __restrict__ ego_status_queue,    // (B,QP,D)
    const void* __restrict__ period,              // (B,QM) int-typed
    const void* __restrict__ mask,                // (B,) bool-typed
    const void* __restrict__ temp_anchor,         // (B,N,T,D)
    const void* __restrict__ temp_mask,           // (B,N,T) bool-typed
    const void* __restrict__ ego_anchor,          // (B,1,T,D)
    const void* __restrict__ ego_mask,            // (B,1,T) bool-typed
    float* __restrict__ out)
{
    __shared__ int s_modes[3];
    if (threadIdx.x == 0) {
        s_modes[0] = detect_float_mode(motion_query);
        s_modes[1] = detect_bool_mode(temp_mask);
        s_modes[2] = detect_period_mode(period);
    }
    __syncthreads();
    const int fm = s_modes[0];
    const int bm = s_modes[1];
    const int pmode = s_modes[2];

    const int stride = (int)(gridDim.x * blockDim.x);

    for (int pack = (int)(blockIdx.x * blockDim.x + threadIdx.x);
         pack < NPACKS; pack += stride) {
        float4 A, B;
        compute_pack(pack, fm, bm, pmode,
                     motion_query, plan_query, ego_status_feature, motion_queue,
                     plan_queue, ego_status_queue, period, mask, temp_anchor,
                     temp_mask, ego_anchor, ego_mask, A, B);
        reinterpret_cast<float4*>(out + pack * 8)[0] = A;
        reinterpret_cast<float4*>(out + pack * 8)[1] = B;
    }
}

extern "C" void kernel_launch(void* const* d_in, const int* in_sizes, int n_in,
                              void* d_out, int out_size, void* d_ws, size_t ws_size,
                              hipStream_t stream) {
    float* out = (float*)d_out;
    const int threads = 256;
    const int blocks = 4096;   // 16 blocks/CU queued, 8 resident -> 32 waves/CU
    state_queue_kernel<<<blocks, threads, 0, stream>>>(
        d_in[0], d_in[1], d_in[2], d_in[3], d_in[4], d_in[5], d_in[6], d_in[7],
        d_in[8], d_in[9], d_in[10], d_in[11], out);
}

// Round 6
// 225.100 us; speedup vs baseline: 1.0303x; 1.0040x over previous
//
#include <hip/hip_runtime.h>
#include <stdint.h>

// Problem constants (B, N, D, QM, QP, NP, T) = (16, 900, 256, 4, 4, 6, 4)
// Storage model (established R0-R3): float arrays are bf16-ROUNDED values in
// FLOAT32 containers; output buffer is FLOAT32. Bool/int input storage is
// detected at runtime (i32 / u8 / bf16 / f32).
//
// R9: segment-specialized blocks (post-mortem of R0/R5/R6):
//  - All prior variants hit ~2.2 TB/s regardless of occupancy (50-53%) or
//    per-wave MLP (2 vs 8 loads) -> not MLP/occupancy-bound. m13 copy = 6.29
//    TB/s on this chip. Difference: our hot loop had an 8-way branch cascade
//    + u32 divisions on every load's dependent path, blocking compiler
//    software-pipelining.
//  - This round: blockIdx ranges map statically to segments. MQ: 2400 blocks
//    x 768 packs (exact), ME: 1800 x 768 (exact) -- straight-line 3-iter
//    fully-unrolled loops, pointer-select (no divergent branch), one
//    magic-mul div pair per iter. Small segments (0.66%): 64 cascade blocks.
//  - Plain write-back stores (R5: NT stores cost +14% HBM writes).
namespace {
constexpr int Bn = 16, Nn = 900, Dn = 256, QMn = 4, QPn = 4, NPn = 6, Tn = 4;

constexpr int SZ_MQ  = Bn * QMn * Nn * Dn;        // 14,745,600
constexpr int SZ_PQ  = Bn * QPn * NPn * Dn;       //     98,304
constexpr int SZ_EQ  = Bn * QPn * Dn;             //     16,384
constexpr int SZ_PER = Bn * QMn;                  //         64
constexpr int SZ_MM  = Bn * (Tn - 1) * Nn;        //     43,200
constexpr int SZ_ME  = Bn * (Tn - 1) * Nn * Dn;   // 11,059,200
constexpr int SZ_PM  = Bn * (Tn - 1);             //         48
constexpr int SZ_PE  = Bn * (Tn - 1) * Dn;        //     12,288

constexpr int OFF_MQ  = 0;
constexpr int OFF_PQ  = OFF_MQ + SZ_MQ;
constexpr int OFF_EQ  = OFF_PQ + SZ_PQ;
constexpr int OFF_PER = OFF_EQ + SZ_EQ;
constexpr int OFF_MM  = OFF_PER + SZ_PER;
constexpr int OFF_ME  = OFF_MM + SZ_MM;
constexpr int OFF_PM  = OFF_ME + SZ_ME;
constexpr int OFF_PE  = OFF_PM + SZ_PM;
constexpr int TOTAL   = OFF_PE + SZ_PE;           // 25,975,088 (divisible by 8)

// Block plan: 256 threads x 3 iters x 8 floats = 6144 floats (768 packs)/block.
constexpr int MQ_BLOCKS    = SZ_MQ / 6144;        // 2400 (exact)
constexpr int ME_BLOCKS    = SZ_ME / 6144;        // 1800 (exact)
constexpr int SMALL_BLOCKS = 64;
constexpr int NUM_BLOCKS   = MQ_BLOCKS + ME_BLOCKS + SMALL_BLOCKS;  // 4264

// Small-segment concatenation: [OFF_PQ, OFF_ME) ++ [OFF_PM, TOTAL)
constexpr int SMALL1       = OFF_ME - OFF_PQ;     // 157,952 floats
constexpr int SMALL_TOTAL  = SMALL1 + (TOTAL - OFF_PM);   // 170,288 floats
constexpr int SMALL_PACKS  = SMALL_TOTAL / 8;     // 21,286
}  // namespace

using u16 = unsigned short;

__device__ __forceinline__ float bits_to_f(unsigned u) {
    return __builtin_bit_cast(float, u);
}

// ---------------- runtime storage-mode detection ----------------
// Float arrays: 0 = f32 container, 1 = bf16 container.
__device__ int detect_float_mode(const void* p) {
    const unsigned* w = (const unsigned*)p;
    int cnt = 0;
#pragma unroll
    for (int i = 0; i < 32; ++i) {
        unsigned ex = (w[i] >> 7) & 0xFFu;   // bf16 exponent field of low halfword
        cnt += (ex >= 120u && ex <= 133u) ? 1 : 0;
    }
    return (cnt >= 16) ? 1 : 0;
}

enum { BM_I32 = 0, BM_U8 = 1, BM_BF16 = 2, BM_F32 = 3 };
__device__ int detect_bool_mode(const void* p) {
    const unsigned* w = (const unsigned*)p;
    unsigned orw = 0, or_even = 0;
    bool hw_ok = true, u8_ok = true;
#pragma unroll
    for (int i = 0; i < 64; ++i) {
        unsigned x = w[i];
        orw |= x;
        unsigned lo = x & 0xFFFFu, hi = x >> 16;
        hw_ok = hw_ok && (lo == 0u || lo == 0x3F80u) && (hi == 0u || hi == 0x3F80u);
        or_even |= lo;
        u8_ok = u8_ok && ((x & 0xFEFEFEFEu) == 0u);
    }
    if (orw <= 1u) return BM_I32;
    if (hw_ok)     return (or_even == 0u) ? BM_F32 : BM_BF16;
    if (u8_ok)     return BM_U8;
    return BM_I32;
}

__device__ __forceinline__ bool get_bool(const void* p, int i, int m) {
    if (m == BM_I32) return ((const int*)p)[i] != 0;
    if (m == BM_U8)  return ((const unsigned char*)p)[i] != 0;
    if (m == BM_BF16) return ((const u16*)p)[i] != 0;
    return ((const unsigned*)p)[i] != 0;     // F32: 0x3F800000 / 0
}

// period (values {0,1,2,3}): 0 = i32, 1 = bf16, 2 = f32.
__device__ int detect_period_mode(const void* p) {
    const unsigned* w = (const unsigned*)p;
    unsigned orw = 0, or_even = 0;
    bool hw_ok = true;
#pragma unroll
    for (int i = 0; i < 16; ++i) {
        unsigned x = w[i];
        orw |= x;
        unsigned lo = x & 0xFFFFu, hi = x >> 16;
        bool lo_ok = (lo == 0u || lo == 0x3F80u || lo == 0x4000u || lo == 0x4040u);
        bool hi_ok = (hi == 0u || hi == 0x3F80u || hi == 0x4000u || hi == 0x4040u);
        hw_ok = hw_ok && lo_ok && hi_ok;
        or_even |= lo;
    }
    if (orw <= 3u) return 0;
    if (hw_ok && or_even == 0u) return 2;
    return 1;
}

__device__ __forceinline__ float get_period_f(const void* p, int i, int m) {
    if (m == 0) return (float)((const int*)p)[i];
    if (m == 1) return bits_to_f((unsigned)((const u16*)p)[i] << 16);
    return ((const float*)p)[i];
}

// Load 8 contiguous float-typed elements starting at element e -> two float4.
__device__ __forceinline__ void load8f(const void* base, int e, int fm,
                                       float4& A, float4& B) {
    if (fm == 0) {
        const float* f = (const float*)base + e;
        A = reinterpret_cast<const float4*>(f)[0];
        B = reinterpret_cast<const float4*>(f)[1];
    } else {
        const int4 r = *reinterpret_cast<const int4*>((const u16*)base + e);
        unsigned x;
        x = (unsigned)r.x; A.x = bits_to_f(x << 16); A.y = bits_to_f(x & 0xFFFF0000u);
        x = (unsigned)r.y; A.z = bits_to_f(x << 16); A.w = bits_to_f(x & 0xFFFF0000u);
        x = (unsigned)r.z; B.x = bits_to_f(x << 16); B.y = bits_to_f(x & 0xFFFF0000u);
        x = (unsigned)r.w; B.z = bits_to_f(x << 16); B.w = bits_to_f(x & 0xFFFF0000u);
    }
}

// Cascade path for the small segments (PQ/EQ/PER/MM/PM/PE) — 0.66% of work.
__device__ void compute_pack_small(
    int idx, int fm, int bm, int pmode,
    const void* __restrict__ plan_query,
    const void* __restrict__ ego_status_feature,
    const void* __restrict__ plan_queue,
    const void* __restrict__ ego_status_queue,
    const void* __restrict__ period,
    const void* __restrict__ mask,
    const void* __restrict__ temp_mask,
    const void* __restrict__ ego_anchor,
    const void* __restrict__ ego_mask,
    float4& A, float4& B)
{
    if (idx < OFF_EQ) {
        // ---- pq
        const int e = idx - OFF_PQ;
        const int d = e & (Dn - 1);
        const unsigned row = (unsigned)(e >> 8);     // (b*QP+q)*NP + p
        const unsigned b = row / (unsigned)(QPn * NPn);
        const unsigned rem = row - b * (unsigned)(QPn * NPn);
        const unsigned q = rem / (unsigned)NPn;
        const unsigned p = rem - q * (unsigned)NPn;
        const bool reset = !get_bool(mask, (int)b, bm);
        if (reset) load8f(plan_query, (((int)b * NPn + (int)p) << 8) + d, fm, A, B);
        else       load8f(plan_queue, e, fm, A, B);
    } else if (idx < OFF_PER) {
        // ---- eq
        const int e = idx - OFF_EQ;
        const int d = e & (Dn - 1);
        const int row = e >> 8;                      // b*QP + q
        const int b = row >> 2;
        const bool reset = !get_bool(mask, b, bm);
        if (reset) load8f(ego_status_feature, (b << 8) + d, fm, A, B);
        else       load8f(ego_status_queue, e, fm, A, B);
    } else if (idx < OFF_MM) {
        // ---- per
        const int e = idx - OFF_PER;
        float h[8];
#pragma unroll
        for (int k = 0; k < 8; ++k) {
            const int g = e + k;
            const int b = g >> 2;
            const bool reset = !get_bool(mask, b, bm);
            h[k] = reset ? 0.0f : get_period_f(period, g, pmode);
        }
        A = make_float4(h[0], h[1], h[2], h[3]);
        B = make_float4(h[4], h[5], h[6], h[7]);
    } else if (idx < OFF_ME) {
        // ---- mm (transposed)
        const int e = idx - OFF_MM;
        float h[8];
#pragma unroll
        for (int k = 0; k < 8; ++k) {
            const unsigned g = (unsigned)(e + k);
            const unsigned b = g / (unsigned)((Tn - 1) * Nn);
            const unsigned rem = g - b * (unsigned)((Tn - 1) * Nn);
            const unsigned t = rem / (unsigned)Nn;
            const unsigned n = rem - t * (unsigned)Nn;
            h[k] = get_bool(temp_mask, ((int)b * Nn + (int)n) * Tn + (int)t, bm)
                       ? 1.0f : 0.0f;
        }
        A = make_float4(h[0], h[1], h[2], h[3]);
        B = make_float4(h[4], h[5], h[6], h[7]);
    } else if (idx < OFF_PE) {
        // ---- pm (transposed, unmodified)
        const int e = idx - OFF_PM;
        float h[8];
#pragma unroll
        for (int k = 0; k < 8; ++k) {
            const unsigned g = (unsigned)(e + k);
            const unsigned b = g / (unsigned)(Tn - 1);
            const unsigned t = g - b * (unsigned)(Tn - 1);
            h[k] = get_bool(ego_mask, (int)b * Tn + (int)t, bm) ? 1.0f : 0.0f;
        }
        A = make_float4(h[0], h[1], h[2], h[3]);
        B = make_float4(h[4], h[5], h[6], h[7]);
    } else {
        // ---- pe (transposed + overwrite)
        const int e = idx - OFF_PE;
        const int d = e & (Dn - 1);
        const unsigned row = (unsigned)(e >> 8);     // b*(T-1) + t
        const unsigned b = row / (unsigned)(Tn - 1);
        const unsigned t = row - b * (unsigned)(Tn - 1);

        bool any_flag = false;
#pragma unroll
        for (int bb = 0; bb < Bn; ++bb) {
            any_flag = any_flag || get_bool(ego_mask, bb * Tn + 0, bm)
                                || get_bool(ego_mask, bb * Tn + 1, bm)
                                || get_bool(ego_mask, bb * Tn + 2, bm);
        }

        const bool p0 = get_bool(ego_mask, (int)b * Tn + 0, bm);
        const bool p1 = get_bool(ego_mask, (int)b * Tn + 1, bm);
        const bool p2 = get_bool(ego_mask, (int)b * Tn + 2, bm);
        const bool all_true = p0 && p1 && p2;
        const int first_false = (!p0) ? 0 : ((!p1) ? 1 : ((!p2) ? 2 : 0));

        const bool overwrite = all_true || ((int)t < first_false);
        int src_t = (int)t;
        if (any_flag && overwrite) src_t = all_true ? (Tn - 1) : first_false;

        load8f(ego_anchor, (((int)b * Tn + src_t) << 8) + d, fm, A, B);
    }
}

__global__ __launch_bounds__(256) void state_queue_kernel(
    const void* __restrict__ motion_query,        // (B,N,D) float-typed
    const void* __restrict__ plan_query,          // (B,NP,D)
    const void* __restrict__ ego_status_feature,  // (B,D)
    const void* __restrict__ motion_queue,        // (B,QM,N,D)
    const void* __restrict__ plan_queue,          // (B,QP,NP,D)
    const void* __restrict__ ego_status_queue,    // (B,QP,D)
    const void* __restrict__ period,              // (B,QM) int-typed
    const void* __restrict__ mask,                // (B,) bool-typed
    const void* __restrict__ temp_anchor,         // (B,N,T,D)
    const void* __restrict__ temp_mask,           // (B,N,T) bool-typed
    const void* __restrict__ ego_anchor,          // (B,1,T,D)
    const void* __restrict__ ego_mask,            // (B,1,T) bool-typed
    float* __restrict__ out)
{
    __shared__ int s_modes[3];
    if (threadIdx.x == 0) {
        s_modes[0] = detect_float_mode(motion_query);
        s_modes[1] = detect_bool_mode(temp_mask);
        s_modes[2] = detect_period_mode(period);
    }
    __syncthreads();
    const int fm = s_modes[0];
    const int bm = s_modes[1];
    const int pmode = s_modes[2];

    const int bx  = (int)blockIdx.x;
    const int tid = (int)threadIdx.x;

    if (bx < MQ_BLOCKS) {
        // ======== MQ: out[b,q,n,d] = mask[b] ? motion_queue[e] : motion_query[b,n,d]
        // 768 packs/block, exactly 3 iterations, no bounds checks.
        const int p0 = bx * 768 + tid;
#pragma unroll
        for (int it = 0; it < 3; ++it) {
            const int e = (p0 + it * 256) * 8;
            const int d = e & (Dn - 1);
            const unsigned row = (unsigned)(e >> 8);          // (b*QM+q)*N + n
            const unsigned bq  = row / (unsigned)Nn;          // magic-mul
            const unsigned n   = row - bq * (unsigned)Nn;
            const unsigned b   = bq >> 2;
            const bool keep = get_bool(mask, (int)b, bm);
            // Pointer/offset select (no divergent branch):
            const void* src = keep ? motion_queue : motion_query;
            const int   off = keep ? e : ((((int)b * Nn + (int)n) << 8) + d);
            float4 A, Bv;
            load8f(src, off, fm, A, Bv);
            reinterpret_cast<float4*>(out + e)[0] = A;
            reinterpret_cast<float4*>(out + e)[1] = Bv;
        }
    } else if (bx < MQ_BLOCKS + ME_BLOCKS) {
        // ======== ME: out[OFF_ME + (b,t,n,d)] = temp_anchor[b,n,t,d], t<T-1
        const int p0 = (bx - MQ_BLOCKS) * 768 + tid;
#pragma unroll
        for (int it = 0; it < 3; ++it) {
            const int e = (p0 + it * 256) * 8;                // local in ME
            const int d = e & (Dn - 1);
            const unsigned row = (unsigned)(e >> 8);          // b*(T-1)*N + t*N + n
            const unsigned b   = row / (unsigned)((Tn - 1) * Nn);
            const unsigned rem = row - b * (unsigned)((Tn - 1) * Nn);
            const unsigned t   = rem / (unsigned)Nn;
            const unsigned n   = rem - t * (unsigned)Nn;
            const int src = ((((int)b * Nn + (int)n) * Tn + (int)t) << 8) + d;
            float4 A, Bv;
            load8f(temp_anchor, src, fm, A, Bv);
            reinterpret_cast<float4*>(out + OFF_ME + e)[0] = A;
            reinterpret_cast<float4*>(out + OFF_ME + e)[1] = Bv;
        }
    } else {
        // ======== small segments: grid-stride cascade over concatenated range
        const int sb = bx - (MQ_BLOCKS + ME_BLOCKS);
        for (int w = sb * 256 + tid; w < SMALL_PACKS; w += SMALL_BLOCKS * 256) {
            const int f = w * 8;
            const int idx = (f < SMALL1) ? (OFF_PQ + f) : (OFF_PM + (f - SMALL1));
            float4 A, Bv;
            compute_pack_small(idx, fm, bm, pmode,
                               plan_query, ego_status_feature, plan_queue,
                               ego_status_queue, period, mask, temp_mask,
                               ego_anchor, ego_mask, A, Bv);
            reinterpret_cast<float4*>(out + idx)[0] = A;
            reinterpret_cast<float4*>(out + idx)[1] = Bv;
        }
    }
}

extern "C" void kernel_launch(void* const* d_in, const int* in_sizes, int n_in,
                              void* d_out, int out_size, void* d_ws, size_t ws_size,
                              hipStream_t stream) {
    float* out = (float*)d_out;
    state_queue_kernel<<<NUM_BLOCKS, 256, 0, stream>>>(
        d_in[0], d_in[1], d_in[2], d_in[3], d_in[4], d_in[5], d_in[6], d_in[7],
        d_in[8], d_in[9], d_in[10], d_in[11], out);
}

// Round 7
// 223.877 us; speedup vs baseline: 1.0359x; 1.0055x over previous
//
#include <hip/hip_runtime.h>
#include <stdint.h>

// Problem constants (B, N, D, QM, QP, NP, T) = (16, 900, 256, 4, 4, 6, 4)
// Storage model (established R0-R3): float arrays are bf16-ROUNDED values in
// FLOAT32 containers; output buffer is FLOAT32. Bool/int input storage is
// detected at runtime (i32 / u8 / bf16 / f32).
//
// R10: per-instruction wave-contiguity fix.
//  - R0/R5/R6/R9 all ~70us @ 2.2 TB/s regardless of structure. Shared flaw:
//    8 floats/thread = two dwordx4 per thread at 32B lane stride -> each wave
//    instruction touches 16 cache lines at 50% coverage (2KB span, holes).
//    m13's 6.29 TB/s copy is 4 floats/thread: 1KB fully contiguous per
//    instruction. R5's NT +14% write amplification corroborates (partial-line
//    NT stores -> HBM RMW).
//  - This round: 4-float chunks. Every load/store instruction covers a
//    contiguous 1KB per wave. 2 chunks/thread (buffer halves) for MLP=2.
//    HALF lands inside MQ -> chunk0 is branch-free MQ path (50% of work).
//  - Plain write-back stores (R5 lesson). All segment sizes are multiples of
//    16 floats -> 4-aligned chunks never straddle segments.
namespace {
constexpr int Bn = 16, Nn = 900, Dn = 256, QMn = 4, QPn = 4, NPn = 6, Tn = 4;

constexpr int SZ_MQ  = Bn * QMn * Nn * Dn;        // 14,745,600
constexpr int SZ_PQ  = Bn * QPn * NPn * Dn;       //     98,304
constexpr int SZ_EQ  = Bn * QPn * Dn;             //     16,384
constexpr int SZ_PER = Bn * QMn;                  //         64
constexpr int SZ_MM  = Bn * (Tn - 1) * Nn;        //     43,200
constexpr int SZ_ME  = Bn * (Tn - 1) * Nn * Dn;   // 11,059,200
constexpr int SZ_PM  = Bn * (Tn - 1);             //         48
constexpr int SZ_PE  = Bn * (Tn - 1) * Dn;        //     12,288

constexpr int OFF_MQ  = 0;
constexpr int OFF_PQ  = OFF_MQ + SZ_MQ;
constexpr int OFF_EQ  = OFF_PQ + SZ_PQ;
constexpr int OFF_PER = OFF_EQ + SZ_EQ;
constexpr int OFF_MM  = OFF_PER + SZ_PER;
constexpr int OFF_ME  = OFF_MM + SZ_MM;
constexpr int OFF_PM  = OFF_ME + SZ_ME;
constexpr int OFF_PE  = OFF_PM + SZ_PM;
constexpr int TOTAL   = OFF_PE + SZ_PE;           // 25,975,088 floats

constexpr int NCHUNKS = TOTAL / 4;                // 6,493,772 four-float chunks
constexpr int HALFC   = NCHUNKS / 2;              // 3,246,886
// HALFC*4 = 12,987,544 < OFF_PQ (14,745,600)  => chunk0 is ALWAYS in MQ.
static_assert(HALFC * 4 < OFF_PQ, "first half must lie inside MQ");
constexpr int THREADS = 256;
constexpr int BLOCKS  = (HALFC + THREADS - 1) / THREADS;   // 12,684
}  // namespace

using u16 = unsigned short;

__device__ __forceinline__ float bits_to_f(unsigned u) {
    return __builtin_bit_cast(float, u);
}

// ---------------- runtime storage-mode detection ----------------
// Float arrays: 0 = f32 container, 1 = bf16 container.
__device__ int detect_float_mode(const void* p) {
    const unsigned* w = (const unsigned*)p;
    int cnt = 0;
#pragma unroll
    for (int i = 0; i < 32; ++i) {
        unsigned ex = (w[i] >> 7) & 0xFFu;   // bf16 exponent field of low halfword
        cnt += (ex >= 120u && ex <= 133u) ? 1 : 0;
    }
    return (cnt >= 16) ? 1 : 0;
}

enum { BM_I32 = 0, BM_U8 = 1, BM_BF16 = 2, BM_F32 = 3 };
__device__ int detect_bool_mode(const void* p) {
    const unsigned* w = (const unsigned*)p;
    unsigned orw = 0, or_even = 0;
    bool hw_ok = true, u8_ok = true;
#pragma unroll
    for (int i = 0; i < 64; ++i) {
        unsigned x = w[i];
        orw |= x;
        unsigned lo = x & 0xFFFFu, hi = x >> 16;
        hw_ok = hw_ok && (lo == 0u || lo == 0x3F80u) && (hi == 0u || hi == 0x3F80u);
        or_even |= lo;
        u8_ok = u8_ok && ((x & 0xFEFEFEFEu) == 0u);
    }
    if (orw <= 1u) return BM_I32;
    if (hw_ok)     return (or_even == 0u) ? BM_F32 : BM_BF16;
    if (u8_ok)     return BM_U8;
    return BM_I32;
}

__device__ __forceinline__ bool get_bool(const void* p, int i, int m) {
    if (m == BM_I32) return ((const int*)p)[i] != 0;
    if (m == BM_U8)  return ((const unsigned char*)p)[i] != 0;
    if (m == BM_BF16) return ((const u16*)p)[i] != 0;
    return ((const unsigned*)p)[i] != 0;     // F32: 0x3F800000 / 0
}

// period (values {0,1,2,3}): 0 = i32, 1 = bf16, 2 = f32.
__device__ int detect_period_mode(const void* p) {
    const unsigned* w = (const unsigned*)p;
    unsigned orw = 0, or_even = 0;
    bool hw_ok = true;
#pragma unroll
    for (int i = 0; i < 16; ++i) {
        unsigned x = w[i];
        orw |= x;
        unsigned lo = x & 0xFFFFu, hi = x >> 16;
        bool lo_ok = (lo == 0u || lo == 0x3F80u || lo == 0x4000u || lo == 0x4040u);
        bool hi_ok = (hi == 0u || hi == 0x3F80u || hi == 0x4000u || hi == 0x4040u);
        hw_ok = hw_ok && lo_ok && hi_ok;
        or_even |= lo;
    }
    if (orw <= 3u) return 0;
    if (hw_ok && or_even == 0u) return 2;
    return 1;
}

__device__ __forceinline__ float get_period_f(const void* p, int i, int m) {
    if (m == 0) return (float)((const int*)p)[i];
    if (m == 1) return bits_to_f((unsigned)((const u16*)p)[i] << 16);
    return ((const float*)p)[i];
}

// Load 4 contiguous float-typed elements at element e -> one float4.
// fm==0: one 16B load (wave: 1KB contiguous). fm==1: one 8B load.
__device__ __forceinline__ void load4f(const void* base, int e, int fm, float4& A) {
    if (fm == 0) {
        A = *reinterpret_cast<const float4*>((const float*)base + e);
    } else {
        const int2 r = *reinterpret_cast<const int2*>((const u16*)base + e);
        unsigned x;
        x = (unsigned)r.x; A.x = bits_to_f(x << 16); A.y = bits_to_f(x & 0xFFFF0000u);
        x = (unsigned)r.y; A.z = bits_to_f(x << 16); A.w = bits_to_f(x & 0xFFFF0000u);
    }
}

// MQ fast path: idx (multiple of 4) inside [0, OFF_PQ).
__device__ __forceinline__ void compute_mq(
    int idx, int fm, int bm,
    const void* __restrict__ motion_query,
    const void* __restrict__ motion_queue,
    const void* __restrict__ mask, float4& A)
{
    const int d = idx & (Dn - 1);
    const unsigned row = (unsigned)(idx >> 8);       // (b*QM+q)*N + n
    const unsigned bq  = row / (unsigned)Nn;         // magic-mul
    const unsigned n   = row - bq * (unsigned)Nn;
    const unsigned b   = bq >> 2;
    const bool keep = get_bool(mask, (int)b, bm);
    const void* src = keep ? motion_queue : motion_query;
    const int   off = keep ? idx : ((((int)b * Nn + (int)n) << 8) + d);
    load4f(src, off, fm, A);
}

// Full cascade for any idx (multiple of 4) in [0, TOTAL).
__device__ void compute_chunk(
    int idx, int fm, int bm, int pmode,
    const void* __restrict__ motion_query,
    const void* __restrict__ plan_query,
    const void* __restrict__ ego_status_feature,
    const void* __restrict__ motion_queue,
    const void* __restrict__ plan_queue,
    const void* __restrict__ ego_status_queue,
    const void* __restrict__ period,
    const void* __restrict__ mask,
    const void* __restrict__ temp_anchor,
    const void* __restrict__ temp_mask,
    const void* __restrict__ ego_anchor,
    const void* __restrict__ ego_mask,
    float4& A)
{
    if (idx < OFF_PQ) {
        compute_mq(idx, fm, bm, motion_query, motion_queue, mask, A);
    } else if (idx < OFF_EQ) {
        // ---- pq
        const int e = idx - OFF_PQ;
        const int d = e & (Dn - 1);
        const unsigned row = (unsigned)(e >> 8);     // (b*QP+q)*NP + p
        const unsigned b = row / (unsigned)(QPn * NPn);
        const unsigned rem = row - b * (unsigned)(QPn * NPn);
        const unsigned q = rem / (unsigned)NPn;
        const unsigned p = rem - q * (unsigned)NPn;
        const bool keep = get_bool(mask, (int)b, bm);
        const void* src = keep ? plan_queue : plan_query;
        const int   off = keep ? e : ((((int)b * NPn + (int)p) << 8) + d);
        load4f(src, off, fm, A);
    } else if (idx < OFF_PER) {
        // ---- eq
        const int e = idx - OFF_EQ;
        const int d = e & (Dn - 1);
        const int row = e >> 8;                      // b*QP + q
        const int b = row >> 2;
        const bool keep = get_bool(mask, b, bm);
        const void* src = keep ? ego_status_queue : ego_status_feature;
        const int   off = keep ? e : ((b << 8) + d);
        load4f(src, off, fm, A);
    } else if (idx < OFF_MM) {
        // ---- per: out[b,q] = reset ? 0 : period[b,q]
        const int e = idx - OFF_PER;
        float h[4];
#pragma unroll
        for (int k = 0; k < 4; ++k) {
            const int g = e + k;
            const int b = g >> 2;
            const bool reset = !get_bool(mask, b, bm);
            h[k] = reset ? 0.0f : get_period_f(period, g, pmode);
        }
        A = make_float4(h[0], h[1], h[2], h[3]);
    } else if (idx < OFF_ME) {
        // ---- mm (transposed): out[b,t,n] = temp_mask[b,n,t], t < T-1
        const int e = idx - OFF_MM;
        float h[4];
#pragma unroll
        for (int k = 0; k < 4; ++k) {
            const unsigned g = (unsigned)(e + k);
            const unsigned b = g / (unsigned)((Tn - 1) * Nn);
            const unsigned rem = g - b * (unsigned)((Tn - 1) * Nn);
            const unsigned t = rem / (unsigned)Nn;
            const unsigned n = rem - t * (unsigned)Nn;
            h[k] = get_bool(temp_mask, ((int)b * Nn + (int)n) * Tn + (int)t, bm)
                       ? 1.0f : 0.0f;
        }
        A = make_float4(h[0], h[1], h[2], h[3]);
    } else if (idx < OFF_PM) {
        // ---- me (transposed): out[b,t,n,d] = temp_anchor[b,n,t,d], t < T-1
        const int e = idx - OFF_ME;
        const int d = e & (Dn - 1);
        const unsigned row = (unsigned)(e >> 8);     // b*(T-1)*N + t*N + n
        const unsigned b = row / (unsigned)((Tn - 1) * Nn);
        const unsigned rem = row - b * (unsigned)((Tn - 1) * Nn);
        const unsigned t = rem / (unsigned)Nn;
        const unsigned n = rem - t * (unsigned)Nn;
        load4f(temp_anchor, ((((int)b * Nn + (int)n) * Tn + (int)t) << 8) + d, fm, A);
    } else if (idx < OFF_PE) {
        // ---- pm (transposed, unmodified): out[b,t,0] = ego_mask[b,0,t]
        const int e = idx - OFF_PM;
        float h[4];
#pragma unroll
        for (int k = 0; k < 4; ++k) {
            const unsigned g = (unsigned)(e + k);
            const unsigned b = g / (unsigned)(Tn - 1);
            const unsigned t = g - b * (unsigned)(Tn - 1);
            h[k] = get_bool(ego_mask, (int)b * Tn + (int)t, bm) ? 1.0f : 0.0f;
        }
        A = make_float4(h[0], h[1], h[2], h[3]);
    } else {
        // ---- pe (transposed + overwrite): out[b,t,0,d]
        const int e = idx - OFF_PE;
        const int d = e & (Dn - 1);
        const unsigned row = (unsigned)(e >> 8);     // b*(T-1) + t
        const unsigned b = row / (unsigned)(Tn - 1);
        const unsigned t = row - b * (unsigned)(Tn - 1);

        bool any_flag = false;
#pragma unroll
        for (int bb = 0; bb < Bn; ++bb) {
            any_flag = any_flag || get_bool(ego_mask, bb * Tn + 0, bm)
                                || get_bool(ego_mask, bb * Tn + 1, bm)
                                || get_bool(ego_mask, bb * Tn + 2, bm);
        }

        const bool p0 = get_bool(ego_mask, (int)b * Tn + 0, bm);
        const bool p1 = get_bool(ego_mask, (int)b * Tn + 1, bm);
        const bool p2 = get_bool(ego_mask, (int)b * Tn + 2, bm);
        const bool all_true = p0 && p1 && p2;
        const int first_false = (!p0) ? 0 : ((!p1) ? 1 : ((!p2) ? 2 : 0));

        const bool overwrite = all_true || ((int)t < first_false);
        int src_t = (int)t;
        if (any_flag && overwrite) src_t = all_true ? (Tn - 1) : first_false;

        load4f(ego_anchor, (((int)b * Tn + src_t) << 8) + d, fm, A);
    }
}

__global__ __launch_bounds__(256) void state_queue_kernel(
    const void* __restrict__ motion_query,        // (B,N,D) float-typed
    const void* __restrict__ plan_query,          // (B,NP,D)
    const void* __restrict__ ego_status_feature,  // (B,D)
    const void* __restrict__ motion_queue,        // (B,QM,N,D)
    const void* __restrict__ plan_queue,          // (B,QP,NP,D)
    const void* __restrict__ ego_status_queue,    // (B,QP,D)
    const void* __restrict__ period,              // (B,QM) int-typed
    const void* __restrict__ mask,                // (B,) bool-typed
    const void* __restrict__ temp_anchor,         // (B,N,T,D)
    const void* __restrict__ temp_mask,           // (B,N,T) bool-typed
    const void* __restrict__ ego_anchor,          // (B,1,T,D)
    const void* __restrict__ ego_mask,            // (B,1,T) bool-typed
    float* __restrict__ out)
{
    __shared__ int s_modes[3];
    if (threadIdx.x == 0) {
        s_modes[0] = detect_float_mode(motion_query);
        s_modes[1] = detect_bool_mode(temp_mask);
        s_modes[2] = detect_period_mode(period);
    }
    __syncthreads();
    const int fm = s_modes[0];
    const int bm = s_modes[1];
    const int pmode = s_modes[2];

    const int c = (int)(blockIdx.x * blockDim.x + threadIdx.x);
    if (c >= HALFC) return;

    // Chunk 0: always MQ (branch-free). Chunk 1: cascade over upper half.
    const int idx0 = c * 4;
    const int idx1 = (c + HALFC) * 4;

    float4 A0, A1;
    compute_mq(idx0, fm, bm, motion_query, motion_queue, mask, A0);
    compute_chunk(idx1, fm, bm, pmode,
                  motion_query, plan_query, ego_status_feature, motion_queue,
                  plan_queue, ego_status_queue, period, mask, temp_anchor,
                  temp_mask, ego_anchor, ego_mask, A1);

    // Wave-contiguous 16B/lane stores (1KB per wave per instruction).
    *reinterpret_cast<float4*>(out + idx0) = A0;
    *reinterpret_cast<float4*>(out + idx1) = A1;
}

extern "C" void kernel_launch(void* const* d_in, const int* in_sizes, int n_in,
                              void* d_out, int out_size, void* d_ws, size_t ws_size,
                              hipStream_t stream) {
    float* out = (float*)d_out;
    state_queue_kernel<<<BLOCKS, THREADS, 0, stream>>>(
        d_in[0], d_in[1], d_in[2], d_in[3], d_in[4], d_in[5], d_in[6], d_in[7],
        d_in[8], d_in[9], d_in[10], d_in[11], out);
}

// Round 8
// 218.355 us; speedup vs baseline: 1.0621x; 1.0253x over previous
//
#include <hip/hip_runtime.h>
#include <stdint.h>

// Problem constants (B, N, D, QM, QP, NP, T) = (16, 900, 256, 4, 4, 6, 4)
// Storage model (established R0-R3): float arrays are bf16-ROUNDED values in
// FLOAT32 containers; output buffer is FLOAT32 (out_size floats). Bool/int
// input storage is detected at runtime (i32 / u8 / bf16 / f32).
//
// R11 = REVERT to the R0 baseline kernel (best measured: 68.0 us dispatch).
// Session conclusion (R5/R6/R9/R10 post-mortems): five structurally
// independent variants all land at 2.15-2.30 TB/s with identical minimal
// traffic (FETCH ~51 MB, WRITE ~101.5 MB = output size). Eliminated:
// branch cascade/divisions (R9), occupancy (R6), per-wave MLP (R5),
// NT stores (R5: +14% write amplification), per-instruction coalescing
// (R10). Little's law: in-flight bytes 17-34 KB/CU >> ~9 KB/CU needed for
// 6.3 TB/s -> not latency-bound. The ~2.2-2.3 TB/s is this 2:1 write:read
// HBM mix's sustained ceiling on this part; R0's structure is the fastest
// and simplest of the band -> final artifact.
namespace {
constexpr int Bn = 16, Nn = 900, Dn = 256, QMn = 4, QPn = 4, NPn = 6, Tn = 4;

constexpr int SZ_MQ  = Bn * QMn * Nn * Dn;        // 14,745,600
constexpr int SZ_PQ  = Bn * QPn * NPn * Dn;       //     98,304
constexpr int SZ_EQ  = Bn * QPn * Dn;             //     16,384
constexpr int SZ_PER = Bn * QMn;                  //         64
constexpr int SZ_MM  = Bn * (Tn - 1) * Nn;        //     43,200
constexpr int SZ_ME  = Bn * (Tn - 1) * Nn * Dn;   // 11,059,200
constexpr int SZ_PM  = Bn * (Tn - 1);             //         48
constexpr int SZ_PE  = Bn * (Tn - 1) * Dn;        //     12,288

constexpr int OFF_MQ  = 0;
constexpr int OFF_PQ  = OFF_MQ + SZ_MQ;
constexpr int OFF_EQ  = OFF_PQ + SZ_PQ;
constexpr int OFF_PER = OFF_EQ + SZ_EQ;
constexpr int OFF_MM  = OFF_PER + SZ_PER;
constexpr int OFF_ME  = OFF_MM + SZ_MM;
constexpr int OFF_PM  = OFF_ME + SZ_ME;
constexpr int OFF_PE  = OFF_PM + SZ_PM;
constexpr int TOTAL   = OFF_PE + SZ_PE;           // 25,975,088 (divisible by 8)
}  // namespace

using u16 = unsigned short;

__device__ __forceinline__ float bits_to_f(unsigned u) {
    return __builtin_bit_cast(float, u);
}

// ---------------- runtime storage-mode detection ----------------
// Float arrays: 0 = f32 container, 1 = bf16 container.
__device__ int detect_float_mode(const void* p) {
    const unsigned* w = (const unsigned*)p;
    int cnt = 0;
#pragma unroll
    for (int i = 0; i < 32; ++i) {
        unsigned ex = (w[i] >> 7) & 0xFFu;   // bf16 exponent field of low halfword
        cnt += (ex >= 120u && ex <= 133u) ? 1 : 0;
    }
    return (cnt >= 16) ? 1 : 0;
}

enum { BM_I32 = 0, BM_U8 = 1, BM_BF16 = 2, BM_F32 = 3 };
__device__ int detect_bool_mode(const void* p) {
    const unsigned* w = (const unsigned*)p;
    unsigned orw = 0, or_even = 0;
    bool hw_ok = true, u8_ok = true;
#pragma unroll
    for (int i = 0; i < 64; ++i) {
        unsigned x = w[i];
        orw |= x;
        unsigned lo = x & 0xFFFFu, hi = x >> 16;
        hw_ok = hw_ok && (lo == 0u || lo == 0x3F80u) && (hi == 0u || hi == 0x3F80u);
        or_even |= lo;
        u8_ok = u8_ok && ((x & 0xFEFEFEFEu) == 0u);
    }
    if (orw <= 1u) return BM_I32;
    if (hw_ok)     return (or_even == 0u) ? BM_F32 : BM_BF16;
    if (u8_ok)     return BM_U8;
    return BM_I32;
}

__device__ __forceinline__ bool get_bool(const void* p, int i, int m) {
    if (m == BM_I32) return ((const int*)p)[i] != 0;
    if (m == BM_U8)  return ((const unsigned char*)p)[i] != 0;
    if (m == BM_BF16) return ((const u16*)p)[i] != 0;
    return ((const unsigned*)p)[i] != 0;     // F32: 0x3F800000 / 0
}

// period (values {0,1,2,3}): 0 = i32, 1 = bf16, 2 = f32.
__device__ int detect_period_mode(const void* p) {
    const unsigned* w = (const unsigned*)p;
    unsigned orw = 0, or_even = 0;
    bool hw_ok = true;
#pragma unroll
    for (int i = 0; i < 16; ++i) {
        unsigned x = w[i];
        orw |= x;
        unsigned lo = x & 0xFFFFu, hi = x >> 16;
        bool lo_ok = (lo == 0u || lo == 0x3F80u || lo == 0x4000u || lo == 0x4040u);
        bool hi_ok = (hi == 0u || hi == 0x3F80u || hi == 0x4000u || hi == 0x4040u);
        hw_ok = hw_ok && lo_ok && hi_ok;
        or_even |= lo;
    }
    if (orw <= 3u) return 0;
    if (hw_ok && or_even == 0u) return 2;
    return 1;
}

__device__ __forceinline__ float get_period_f(const void* p, int i, int m) {
    if (m == 0) return (float)((const int*)p)[i];
    if (m == 1) return bits_to_f((unsigned)((const u16*)p)[i] << 16);
    return ((const float*)p)[i];
}

// Load 8 contiguous float-typed elements starting at element e -> two float4.
__device__ __forceinline__ void load8f(const void* base, int e, int fm,
                                       float4& A, float4& B) {
    if (fm == 0) {
        const float* f = (const float*)base + e;
        A = reinterpret_cast<const float4*>(f)[0];
        B = reinterpret_cast<const float4*>(f)[1];
    } else {
        const int4 r = *reinterpret_cast<const int4*>((const u16*)base + e);
        unsigned x;
        x = (unsigned)r.x; A.x = bits_to_f(x << 16); A.y = bits_to_f(x & 0xFFFF0000u);
        x = (unsigned)r.y; A.z = bits_to_f(x << 16); A.w = bits_to_f(x & 0xFFFF0000u);
        x = (unsigned)r.z; B.x = bits_to_f(x << 16); B.y = bits_to_f(x & 0xFFFF0000u);
        x = (unsigned)r.w; B.z = bits_to_f(x << 16); B.w = bits_to_f(x & 0xFFFF0000u);
    }
}

__global__ __launch_bounds__(256) void state_queue_kernel(
    const void* __restrict__ motion_query,        // (B,N,D) float-typed
    const void* __restrict__ plan_query,          // (B,NP,D)
    const void* __restrict__ ego_status_feature,  // (B,D)
    const void* __restrict__ motion_queue,        // (B,QM,N,D)
    const void* __restrict__ plan_queue,          // (B,QP,NP,D)
    const void* __restrict__ ego_status_queue,    // (B,QP,D)
    const void* __restrict__ period,              // (B,QM) int-typed
    const void* __restrict__ mask,                // (B,) bool-typed
    const void* __restrict__ temp_anchor,         // (B,N,T,D)
    const void* __restrict__ temp_mask,           // (B,N,T) bool-typed
    const void* __restrict__ ego_anchor,          // (B,1,T,D)
    const void* __restrict__ ego_mask,            // (B,1,T) bool-typed
    float* __restrict__ out)
{
    __shared__ int s_modes[3];
    if (threadIdx.x == 0) {
        s_modes[0] = detect_float_mode(motion_query);
        s_modes[1] = detect_bool_mode(temp_mask);
        s_modes[2] = detect_period_mode(period);
    }
    __syncthreads();
    const int fm = s_modes[0];
    const int bm = s_modes[1];
    const int pmode = s_modes[2];

    const int pack = blockIdx.x * blockDim.x + threadIdx.x;
    const int idx = pack * 8;
    if (idx >= TOTAL) return;

    float4 A, B;

    if (idx < OFF_PQ) {
        // ---- mq: out[b,q,n,d] = reset ? motion_query[b,n,d] : motion_queue[b,q,n,d]
        const int e = idx - OFF_MQ;
        const int d = e & (Dn - 1);
        const unsigned row = (unsigned)(e >> 8);     // (b*QM+q)*N + n
        const unsigned bq = row / (unsigned)Nn;
        const unsigned n = row - bq * (unsigned)Nn;
        const unsigned b = bq >> 2;
        const bool reset = !get_bool(mask, (int)b, bm);
        if (reset) load8f(motion_query, (((int)b * Nn + (int)n) << 8) + d, fm, A, B);
        else       load8f(motion_queue, e, fm, A, B);
    } else if (idx < OFF_EQ) {
        // ---- pq
        const int e = idx - OFF_PQ;
        const int d = e & (Dn - 1);
        const unsigned row = (unsigned)(e >> 8);     // (b*QP+q)*NP + p
        const unsigned b = row / (unsigned)(QPn * NPn);
        const unsigned rem = row - b * (unsigned)(QPn * NPn);
        const unsigned q = rem / (unsigned)NPn;
        const unsigned p = rem - q * (unsigned)NPn;
        const bool reset = !get_bool(mask, (int)b, bm);
        if (reset) load8f(plan_query, (((int)b * NPn + (int)p) << 8) + d, fm, A, B);
        else       load8f(plan_queue, e, fm, A, B);
    } else if (idx < OFF_PER) {
        // ---- eq
        const int e = idx - OFF_EQ;
        const int d = e & (Dn - 1);
        const int row = e >> 8;                      // b*QP + q
        const int b = row >> 2;
        const bool reset = !get_bool(mask, b, bm);
        if (reset) load8f(ego_status_feature, (b << 8) + d, fm, A, B);
        else       load8f(ego_status_queue, e, fm, A, B);
    } else if (idx < OFF_MM) {
        // ---- per: out[b,q] = reset ? 0 : period[b,q]
        const int e = idx - OFF_PER;
        float h[8];
#pragma unroll
        for (int k = 0; k < 8; ++k) {
            const int g = e + k;
            const int b = g >> 2;
            const bool reset = !get_bool(mask, b, bm);
            h[k] = reset ? 0.0f : get_period_f(period, g, pmode);
        }
        A = make_float4(h[0], h[1], h[2], h[3]);
        B = make_float4(h[4], h[5], h[6], h[7]);
    } else if (idx < OFF_ME) {
        // ---- mm (transposed): out[b,t,n] = temp_mask[b,n,t], t < T-1
        const int e = idx - OFF_MM;
        float h[8];
#pragma unroll
        for (int k = 0; k < 8; ++k) {
            const unsigned g = (unsigned)(e + k);
            const unsigned b = g / (unsigned)((Tn - 1) * Nn);
            const unsigned rem = g - b * (unsigned)((Tn - 1) * Nn);
            const unsigned t = rem / (unsigned)Nn;
            const unsigned n = rem - t * (unsigned)Nn;
            h[k] = get_bool(temp_mask, ((int)b * Nn + (int)n) * Tn + (int)t, bm)
                       ? 1.0f : 0.0f;
        }
        A = make_float4(h[0], h[1], h[2], h[3]);
        B = make_float4(h[4], h[5], h[6], h[7]);
    } else if (idx < OFF_PM) {
        // ---- me (transposed): out[b,t,n,d] = temp_anchor[b,n,t,d], t < T-1
        const int e = idx - OFF_ME;
        const int d = e & (Dn - 1);
        const unsigned row = (unsigned)(e >> 8);     // b*(T-1)*N + t*N + n
        const unsigned b = row / (unsigned)((Tn - 1) * Nn);
        const unsigned rem = row - b * (unsigned)((Tn - 1) * Nn);
        const unsigned t = rem / (unsigned)Nn;
        const unsigned n = rem - t * (unsigned)Nn;
        load8f(temp_anchor, ((((int)b * Nn + (int)n) * Tn + (int)t) << 8) + d, fm, A, B);
    } else if (idx < OFF_PE) {
        // ---- pm (transposed, unmodified): out[b,t,0] = ego_mask[b,0,t]
        const int e = idx - OFF_PM;
        float h[8];
#pragma unroll
        for (int k = 0; k < 8; ++k) {
            const unsigned g = (unsigned)(e + k);
            const unsigned b = g / (unsigned)(Tn - 1);
            const unsigned t = g - b * (unsigned)(Tn - 1);
            h[k] = get_bool(ego_mask, (int)b * Tn + (int)t, bm) ? 1.0f : 0.0f;
        }
        A = make_float4(h[0], h[1], h[2], h[3]);
        B = make_float4(h[4], h[5], h[6], h[7]);
    } else {
        // ---- pe (transposed + overwrite): out[b,t,0,d]
        const int e = idx - OFF_PE;
        const int d = e & (Dn - 1);
        const unsigned row = (unsigned)(e >> 8);     // b*(T-1) + t
        const unsigned b = row / (unsigned)(Tn - 1);
        const unsigned t = row - b * (unsigned)(Tn - 1);

        bool any_flag = false;
#pragma unroll
        for (int bb = 0; bb < Bn; ++bb) {
            any_flag = any_flag || get_bool(ego_mask, bb * Tn + 0, bm)
                                || get_bool(ego_mask, bb * Tn + 1, bm)
                                || get_bool(ego_mask, bb * Tn + 2, bm);
        }

        const bool p0 = get_bool(ego_mask, (int)b * Tn + 0, bm);
        const bool p1 = get_bool(ego_mask, (int)b * Tn + 1, bm);
        const bool p2 = get_bool(ego_mask, (int)b * Tn + 2, bm);
        const bool all_true = p0 && p1 && p2;
        const int first_false = (!p0) ? 0 : ((!p1) ? 1 : ((!p2) ? 2 : 0));

        const bool overwrite = all_true || ((int)t < first_false);
        int src_t = (int)t;
        if (any_flag && overwrite) src_t = all_true ? (Tn - 1) : first_false;

        load8f(ego_anchor, (((int)b * Tn + src_t) << 8) + d, fm, A, B);
    }

    reinterpret_cast<float4*>(out + idx)[0] = A;
    reinterpret_cast<float4*>(out + idx)[1] = B;
}

extern "C" void kernel_launch(void* const* d_in, const int* in_sizes, int n_in,
                              void* d_out, int out_size, void* d_ws, size_t ws_size,
                              hipStream_t stream) {
    float* out = (float*)d_out;
    const int packs = TOTAL / 8;               // 3,246,886
    const int threads = 256;
    const int blocks = (packs + threads - 1) / threads;
    state_queue_kernel<<<blocks, threads, 0, stream>>>(
        d_in[0], d_in[1], d_in[2], d_in[3], d_in[4], d_in[5], d_in[6], d_in[7],
        d_in[8], d_in[9], d_in[10], d_in[11], out);
}